// Round 12
// baseline (148.702 us; speedup 1.0000x reference)
//
#include <hip/hip_runtime.h>
#include <hip/hip_bf16.h>

typedef __bf16 bf16x8_t __attribute__((ext_vector_type(8)));
typedef float f32x4_t __attribute__((ext_vector_type(4)));

#define SCALE_ZB 7.2134752044448169f   // 5 * log2(e): logits in log2 domain
#define LN2 0.69314718055994531f
#define E2(x) __builtin_amdgcn_exp2f(x)
#define LG2(x) __builtin_amdgcn_logf(x)

// ws byte offsets
#define WS_CNT    256u       // int[2048]
#define WS_BASE   8448u      // int[2048]
#define WS_CUR    16640u     // int[2048]
#define WS_PERM   24832u     // int[65536]
#define WS_ANC    294912u    // bf16[262144] (512 KB), B-fragment order
#define WS_PART   819200u    // float2[65536*8] = 4 MB
#define WS_WSUM   5013504u   // float4[16384] = 256 KB (hp,pos,zsq,cent per wave)
#define WS_LSE    5275648u   // float[256]
#define WS_ZERO   8448u      // zero cnt region only

__device__ __forceinline__ void gload_lds16(const void* g, void* l) {
    __builtin_amdgcn_global_load_lds((const __attribute__((address_space(1))) unsigned int*)g,
                                     (__attribute__((address_space(3))) unsigned int*)l,
                                     16, 0, 0);
}

// ---- anchors f32 -> bf16 packed in MFMA B-fragment order + label histogram ----
// layout: [chunk c 0..127][kk 0..3][lane 0..63][e 0..7]
__global__ void prepHist(const float* __restrict__ anc, __bf16* __restrict__ out,
                         const int* __restrict__ labels, int* __restrict__ cnt) {
    int i = blockIdx.x * 256 + threadIdx.x;   // 0..65535
    atomicAdd(&cnt[labels[i]], 1);
    if (i < 32768) {
        int m = i >> 4, k0 = (i & 15) << 3;
        int kk = k0 >> 5, g = (k0 >> 3) & 3, l15 = m & 15, c = m >> 4;
        int lane = (g << 4) | l15;
        int base = (((c << 2) + kk) << 9) + (lane << 3);
        const float4* a4 = (const float4*)anc + (size_t)m * 32 + (k0 >> 2);
        float4 f0 = a4[0], f1 = a4[1];
        bf16x8_t pk;
        pk[0] = (__bf16)f0.x; pk[1] = (__bf16)f0.y; pk[2] = (__bf16)f0.z; pk[3] = (__bf16)f0.w;
        pk[4] = (__bf16)f1.x; pk[5] = (__bf16)f1.y; pk[6] = (__bf16)f1.z; pk[7] = (__bf16)f1.w;
        *(bf16x8_t*)&out[base] = pk;
    }
}

__global__ void scanK(const int* __restrict__ cnt, int* __restrict__ base,
                      int* __restrict__ cursor) {
    __shared__ int wsum[4];
    int t = threadIdx.x, lane = t & 63, w = t >> 6;
    int c[8], tot = 0;
    #pragma unroll
    for (int q = 0; q < 8; ++q) { c[q] = cnt[t * 8 + q]; tot += c[q]; }
    int sc = tot;
    #pragma unroll
    for (int off = 1; off < 64; off <<= 1) {
        int o = __shfl_up(sc, off);
        if (lane >= off) sc += o;
    }
    if (lane == 63) wsum[w] = sc;
    __syncthreads();
    int woff = 0;
    for (int ww = 0; ww < w; ++ww) woff += wsum[ww];
    int ex = woff + sc - tot;
    #pragma unroll
    for (int q = 0; q < 8; ++q) {
        base[t * 8 + q] = ex;
        cursor[t * 8 + q] = ex;
        ex += c[q];
    }
}

__global__ void scatK(const int* __restrict__ labels, int* __restrict__ cursor,
                      int* __restrict__ perm) {
    int i = blockIdx.x * 256 + threadIdx.x;
    int l = labels[i];
    int p = atomicAdd(&cursor[l], 1);
    perm[p] = i;
}

// 2048 blocks x 8 waves. Block = (row-block rb of 256 rows) x (M-eighth e).
// 64 KB LDS stages eighth e once (global_load_lds under prologue); ONE barrier;
// main loop LDS-only. Zero global atomics. Wave w owns rows rb*256+w*32..+32.
__launch_bounds__(512, 4)
__global__ void fusedF(const float* __restrict__ z,
                       const float* __restrict__ he,
                       const float* __restrict__ hc,
                       const float* __restrict__ ancf,
                       const int* __restrict__ labels,
                       const __bf16* __restrict__ ancb,
                       const int* __restrict__ cnt,
                       const int* __restrict__ basep,
                       const int* __restrict__ perm,
                       float4* __restrict__ wsum,
                       float2* __restrict__ part) {
    __shared__ __bf16 bsm[32768];   // 64 KB = 16 chunks

    const int tid  = threadIdx.x;
    const int lane = tid & 63;
    const int w    = tid >> 6;
    const int l15  = lane & 15, g = lane >> 4;
    const int bid  = blockIdx.x;
    const int rb   = bid >> 3;
    const int e    = bid & 7;
    const int R0   = (rb << 8) + (w << 5);   // wave's 32 rows

    // ---- stage eighth e -> LDS, issued FIRST (lands under prologue) ----
    {
        const __bf16* src = ancb + (e << 15) + (w << 12);
        #pragma unroll
        for (int i = 0; i < 8; ++i)
            gload_lds16(src + (i << 9) + (lane << 3), &bsm[(w << 12) + (i << 9)]);
    }

    // ---- h-align slice ----
    float hp = 0.f;
    {
        int gt = (bid << 9) + tid;           // 0..1048575
        const float4* hev = (const float4*)he;
        const float4* hcv = (const float4*)hc;
        #pragma unroll
        for (int i = 0; i < 4; ++i) {
            float4 ev = hev[(size_t)i * 1048576 + gt];
            float4 cv = hcv[(size_t)i * 1048576 + gt];
            float dx = ev.x - cv.x, dy = ev.y - cv.y, dz = ev.z - cv.z, dw = ev.w - cv.w;
            hp += dx * dx + dy * dy + dz * dz + dw * dw;
        }
    }

    // ---- A-fragments from z; e0 pos-dot, e1 zsq ----
    bf16x8_t Af[2][4];
    float sp = 0.f;
    #pragma unroll
    for (int rf = 0; rf < 2; ++rf) {
        int row = R0 + (rf << 4) + l15;
        const float4* zr = (const float4*)z + ((size_t)row << 5);
        const float4* ar;
        if (e == 0) {
            int lb = labels[row];
            ar = (const float4*)ancf + ((size_t)lb << 5);
        }
        #pragma unroll
        for (int kk = 0; kk < 4; ++kk) {
            int qq = (kk << 3) + (g << 1);
            float4 z0 = zr[qq], z1 = zr[qq + 1];
            if (e == 0) {
                float4 a0 = ar[qq], a1 = ar[qq + 1];
                sp += z0.x*a0.x + z0.y*a0.y + z0.z*a0.z + z0.w*a0.w
                    + z1.x*a1.x + z1.y*a1.y + z1.z*a1.z + z1.w*a1.w;
            } else if (e == 1) {
                sp += z0.x*z0.x + z0.y*z0.y + z0.z*z0.z + z0.w*z0.w
                    + z1.x*z1.x + z1.y*z1.y + z1.z*z1.z + z1.w*z1.w;
            }
            bf16x8_t pk;
            pk[0] = (__bf16)(z0.x * SCALE_ZB); pk[1] = (__bf16)(z0.y * SCALE_ZB);
            pk[2] = (__bf16)(z0.z * SCALE_ZB); pk[3] = (__bf16)(z0.w * SCALE_ZB);
            pk[4] = (__bf16)(z1.x * SCALE_ZB); pk[5] = (__bf16)(z1.y * SCALE_ZB);
            pk[6] = (__bf16)(z1.z * SCALE_ZB); pk[7] = (__bf16)(z1.w * SCALE_ZB);
            Af[rf][kk] = pk;
        }
    }
    #pragma unroll
    for (int off = 32; off; off >>= 1) {
        sp += __shfl_xor(sp, off);
        hp += __shfl_xor(hp, off);
    }

    asm volatile("s_waitcnt vmcnt(0)" ::: "memory");
    __syncthreads();   // LDS eighth resident; the ONLY barrier

    // ---- main loop: 16 chunks (8 pairs), LDS-only, batched-2 LSE ----
    float ms[2][4], ss[2][4];
    #pragma unroll
    for (int f = 0; f < 2; ++f)
        #pragma unroll
        for (int r = 0; r < 4; ++r) { ms[f][r] = -1.0e30f; ss[f][r] = 0.f; }

    for (int c = 0; c < 16; c += 2) {
        f32x4_t a00 = {0.f,0.f,0.f,0.f}, a01 = {0.f,0.f,0.f,0.f};
        {
            bf16x8_t B0[4];
            #pragma unroll
            for (int kk = 0; kk < 4; ++kk)
                B0[kk] = *(const bf16x8_t*)&bsm[(((c << 2) | kk) << 9) + (lane << 3)];
            #pragma unroll
            for (int kk = 0; kk < 4; ++kk) {
                a00 = __builtin_amdgcn_mfma_f32_16x16x32_bf16(Af[0][kk], B0[kk], a00, 0, 0, 0);
                a01 = __builtin_amdgcn_mfma_f32_16x16x32_bf16(Af[1][kk], B0[kk], a01, 0, 0, 0);
            }
        }
        f32x4_t a10 = {0.f,0.f,0.f,0.f}, a11 = {0.f,0.f,0.f,0.f};
        {
            bf16x8_t B1[4];
            #pragma unroll
            for (int kk = 0; kk < 4; ++kk)
                B1[kk] = *(const bf16x8_t*)&bsm[((((c + 1) << 2) | kk) << 9) + (lane << 3)];
            #pragma unroll
            for (int kk = 0; kk < 4; ++kk) {
                a10 = __builtin_amdgcn_mfma_f32_16x16x32_bf16(Af[0][kk], B1[kk], a10, 0, 0, 0);
                a11 = __builtin_amdgcn_mfma_f32_16x16x32_bf16(Af[1][kk], B1[kk], a11, 0, 0, 0);
            }
        }
        #pragma unroll
        for (int r = 0; r < 4; ++r) {
            {
                float v0 = a00[r], v1 = a10[r];
                float nm = fmaxf(fmaxf(v0, v1), ms[0][r]);
                ss[0][r] = ss[0][r] * E2(ms[0][r] - nm) + E2(v0 - nm) + E2(v1 - nm);
                ms[0][r] = nm;
            }
            {
                float v0 = a01[r], v1 = a11[r];
                float nm = fmaxf(fmaxf(v0, v1), ms[1][r]);
                ss[1][r] = ss[1][r] * E2(ms[1][r] - nm) + E2(v0 - nm) + E2(v1 - nm);
                ms[1][r] = nm;
            }
        }
    }

    // ---- merge (m,s) across the 16 anchor-lanes; write eighth partials ----
    #pragma unroll
    for (int f = 0; f < 2; ++f)
        #pragma unroll
        for (int r = 0; r < 4; ++r) {
            float m = ms[f][r], s = ss[f][r];
            #pragma unroll
            for (int off = 1; off < 16; off <<= 1) {
                float om = __shfl_xor(m, off), os = __shfl_xor(s, off);
                float nm = fmaxf(m, om);
                s = s * E2(m - nm) + os * E2(om - nm);
                m = nm;
            }
            ms[f][r] = m; ss[f][r] = s;
        }
    if (l15 == 0) {
        #pragma unroll
        for (int f = 0; f < 2; ++f)
            #pragma unroll
            for (int r = 0; r < 4; ++r) {
                int row0 = R0 + (f << 4) + (g << 2) + r;
                part[(row0 << 3) + e] = make_float2(ms[f][r], ss[f][r]);
            }
    }

    // ---- centroid tail: wave 3 handles label bid ----
    float centv = 0.f;
    if (w == 3) {
        const int n = cnt[bid], bs = basep[bid];
        float ax = 0.f, ay = 0.f;
        const float2* z2 = (const float2*)z;
        for (int e0 = 0; e0 < n; e0 += 64) {
            int pe = (e0 + lane < n) ? perm[bs + e0 + lane] : 0;
            int c2 = n - e0; if (c2 > 64) c2 = 64;
            int j = 0;
            for (; j + 3 < c2; j += 4) {
                int r0 = __shfl(pe, j), r1 = __shfl(pe, j + 1);
                int r2 = __shfl(pe, j + 2), r3 = __shfl(pe, j + 3);
                float2 v0 = z2[((size_t)r0 << 6) + lane];
                float2 v1 = z2[((size_t)r1 << 6) + lane];
                float2 v2 = z2[((size_t)r2 << 6) + lane];
                float2 v3 = z2[((size_t)r3 << 6) + lane];
                ax += v0.x + v1.x + v2.x + v3.x;
                ay += v0.y + v1.y + v2.y + v3.y;
            }
            for (; j < c2; ++j) {
                int r0 = __shfl(pe, j);
                float2 v0 = z2[((size_t)r0 << 6) + lane];
                ax += v0.x; ay += v0.y;
            }
        }
        float ssq = ax * ax + ay * ay;
        #pragma unroll
        for (int off = 32; off; off >>= 1) ssq += __shfl_xor(ssq, off);
        centv = ssq / fmaxf((float)n, 1.f);
    }

    // ---- per-wave slot store (no atomics) ----
    if (lane == 0) {
        float4 o;
        o.x = hp;
        o.y = (e == 0) ? sp : 0.f;
        o.z = (e == 1) ? sp : 0.f;
        o.w = centv;
        wsum[(bid << 3) | w] = o;
    }
}

// ---- merge the eight M-eighth partials per row -> per-block lse partial ----
__global__ void mergeL(const float4* __restrict__ part4, float* __restrict__ lsePart) {
    __shared__ float wpart[4];
    int t = blockIdx.x * 256 + threadIdx.x;   // 0..65535 rows
    float4 P0 = part4[(t << 2)], P1 = part4[(t << 2) + 1];
    float4 P2 = part4[(t << 2) + 2], P3 = part4[(t << 2) + 3];
    float nm = fmaxf(fmaxf(fmaxf(P0.x, P0.z), fmaxf(P1.x, P1.z)),
                     fmaxf(fmaxf(P2.x, P2.z), fmaxf(P3.x, P3.z)));
    float s = P0.y * E2(P0.x - nm) + P0.w * E2(P0.z - nm)
            + P1.y * E2(P1.x - nm) + P1.w * E2(P1.z - nm)
            + P2.y * E2(P2.x - nm) + P2.w * E2(P2.z - nm)
            + P3.y * E2(P3.x - nm) + P3.w * E2(P3.z - nm);
    float lse = nm + LG2(s);
    #pragma unroll
    for (int off = 32; off; off >>= 1) lse += __shfl_xor(lse, off);
    if ((threadIdx.x & 63) == 0) wpart[threadIdx.x >> 6] = lse;
    __syncthreads();
    if (threadIdx.x == 0)
        lsePart[blockIdx.x] = wpart[0] + wpart[1] + wpart[2] + wpart[3];
}

// ---- final reduction: 16384 wave slots + 256 lse partials ----
__global__ void finalR(const float4* __restrict__ wsum,
                       const float* __restrict__ lsePart,
                       float* __restrict__ out) {
    __shared__ float red[5][4];
    int t = threadIdx.x, lane = t & 63, w = t >> 6;
    float hp = 0.f, pos = 0.f, zsq = 0.f, cent = 0.f, lse = 0.f;
    #pragma unroll
    for (int i = 0; i < 64; ++i) {
        float4 v = wsum[i * 256 + t];
        hp += v.x; pos += v.y; zsq += v.z; cent += v.w;
    }
    lse = lsePart[t];
    #pragma unroll
    for (int off = 32; off; off >>= 1) {
        hp  += __shfl_xor(hp, off);
        pos += __shfl_xor(pos, off);
        zsq += __shfl_xor(zsq, off);
        cent += __shfl_xor(cent, off);
        lse += __shfl_xor(lse, off);
    }
    if (lane == 0) {
        red[0][w] = hp; red[1][w] = pos; red[2][w] = zsq; red[3][w] = cent; red[4][w] = lse;
    }
    __syncthreads();
    if (t == 0) {
        float H = red[0][0] + red[0][1] + red[0][2] + red[0][3];
        float P = red[1][0] + red[1][1] + red[1][2] + red[1][3];
        float Z = red[2][0] + red[2][1] + red[2][2] + red[2][3];
        float C = red[3][0] + red[3][1] + red[3][2] + red[3][3];
        float L = red[4][0] + red[4][1] + red[4][2] + red[4][3];
        float lc    = (LN2 * L - 5.0f * P) * (1.0f / 65536.0f);
        float cent2 = (Z - C) * (1.0f / 8388608.0f);
        float hal   = H * (1.0f / 16777216.0f);
        out[0] = lc + 0.05f * cent2 + 0.1f * hal;
    }
}

extern "C" void kernel_launch(void* const* d_in, const int* in_sizes, int n_in,
                              void* d_out, int out_size, void* d_ws, size_t ws_size,
                              hipStream_t stream) {
    const float* z      = (const float*)d_in[0];
    const float* he     = (const float*)d_in[1];
    const float* hc     = (const float*)d_in[2];
    const float* anc    = (const float*)d_in[3];
    const int*   labels = (const int*)d_in[4];

    char* ws = (char*)d_ws;
    int*    cnt     = (int*)(ws + WS_CNT);
    int*    basep   = (int*)(ws + WS_BASE);
    int*    cursor  = (int*)(ws + WS_CUR);
    int*    perm    = (int*)(ws + WS_PERM);
    __bf16* ancb    = (__bf16*)(ws + WS_ANC);
    float2* part    = (float2*)(ws + WS_PART);
    float4* wsum    = (float4*)(ws + WS_WSUM);
    float*  lsePart = (float*)(ws + WS_LSE);

    hipMemsetAsync(d_ws, 0, WS_ZERO, stream);
    prepHist<<<256, 256, 0, stream>>>(anc, ancb, labels, cnt);
    scanK<<<1, 256, 0, stream>>>(cnt, basep, cursor);
    scatK<<<256, 256, 0, stream>>>(labels, cursor, perm);
    fusedF<<<2048, 512, 0, stream>>>(z, he, hc, anc, labels, ancb, cnt, basep, perm, wsum, part);
    mergeL<<<256, 256, 0, stream>>>((const float4*)part, lsePart);
    finalR<<<1, 256, 0, stream>>>(wsum, lsePart, (float*)d_out);
}

// Round 13
// 144.980 us; speedup vs baseline: 1.0257x; 1.0257x over previous
//
#include <hip/hip_runtime.h>
#include <hip/hip_bf16.h>

typedef __bf16 bf16x8_t __attribute__((ext_vector_type(8)));
typedef float f32x4_t __attribute__((ext_vector_type(4)));

#define SCALE_ZB 7.2134752044448169f   // 5 * log2(e): logits in log2 domain
#define LN2 0.69314718055994531f
#define E2(x) __builtin_amdgcn_exp2f(x)
#define LG2(x) __builtin_amdgcn_logf(x)

// ws byte offsets
#define WS_CNT    256u       // int[2048]
#define WS_BASE   8448u      // int[2048]
#define WS_CUR    16640u     // int[2048]
#define WS_PERM   24832u     // int[65536]
#define WS_ANC    294912u    // bf16[262144] (512 KB), B-fragment order
#define WS_PART   819200u    // float2[65536*4] = 2 MB
#define WS_WSUM   2916352u   // float4[4096] (hp,pos,zsq,cent per wave)
#define WS_LSE    2981888u   // float[256]
#define WS_ZERO   8448u      // zero cnt region only

// ---- anchors f32 -> bf16 packed in MFMA B-fragment order + label histogram ----
// layout: [chunk c 0..127][kk 0..3][lane 0..63][e 0..7]
__global__ void prepHist(const float* __restrict__ anc, __bf16* __restrict__ out,
                         const int* __restrict__ labels, int* __restrict__ cnt) {
    int i = blockIdx.x * 256 + threadIdx.x;   // 0..65535
    atomicAdd(&cnt[labels[i]], 1);
    if (i < 32768) {
        int m = i >> 4, k0 = (i & 15) << 3;
        int kk = k0 >> 5, g = (k0 >> 3) & 3, l15 = m & 15, c = m >> 4;
        int lane = (g << 4) | l15;
        int base = (((c << 2) + kk) << 9) + (lane << 3);
        const float4* a4 = (const float4*)anc + (size_t)m * 32 + (k0 >> 2);
        float4 f0 = a4[0], f1 = a4[1];
        bf16x8_t pk;
        pk[0] = (__bf16)f0.x; pk[1] = (__bf16)f0.y; pk[2] = (__bf16)f0.z; pk[3] = (__bf16)f0.w;
        pk[4] = (__bf16)f1.x; pk[5] = (__bf16)f1.y; pk[6] = (__bf16)f1.z; pk[7] = (__bf16)f1.w;
        *(bf16x8_t*)&out[base] = pk;
    }
}

__global__ void scanK(const int* __restrict__ cnt, int* __restrict__ base,
                      int* __restrict__ cursor) {
    __shared__ int wsum[4];
    int t = threadIdx.x, lane = t & 63, w = t >> 6;
    int c[8], tot = 0;
    #pragma unroll
    for (int q = 0; q < 8; ++q) { c[q] = cnt[t * 8 + q]; tot += c[q]; }
    int sc = tot;
    #pragma unroll
    for (int off = 1; off < 64; off <<= 1) {
        int o = __shfl_up(sc, off);
        if (lane >= off) sc += o;
    }
    if (lane == 63) wsum[w] = sc;
    __syncthreads();
    int woff = 0;
    for (int ww = 0; ww < w; ++ww) woff += wsum[ww];
    int ex = woff + sc - tot;
    #pragma unroll
    for (int q = 0; q < 8; ++q) {
        base[t * 8 + q] = ex;
        cursor[t * 8 + q] = ex;
        ex += c[q];
    }
}

__global__ void scatK(const int* __restrict__ labels, int* __restrict__ cursor,
                      int* __restrict__ perm) {
    int i = blockIdx.x * 256 + threadIdx.x;
    int l = labels[i];
    int p = atomicAdd(&cursor[l], 1);
    perm[p] = i;
}

// 1024 blocks x 4 waves. Block = 64 rows; wave q = M-quarter (512 anchors).
// No LDS, no barriers, no global atomics. Waves 2,3 also gather one label each.
__launch_bounds__(256)
__global__ void uniK2(const float* __restrict__ z,
                      const float* __restrict__ he,
                      const float* __restrict__ hc,
                      const float* __restrict__ ancf,
                      const int* __restrict__ labels,
                      const __bf16* __restrict__ ancb,
                      const int* __restrict__ cnt,
                      const int* __restrict__ basep,
                      const int* __restrict__ perm,
                      float4* __restrict__ wsum,
                      float2* __restrict__ part) {
    const int tid  = threadIdx.x;
    const int lane = tid & 63;
    const int q    = tid >> 6;          // wave = M-quarter
    const int bid  = blockIdx.x;
    const int l15  = lane & 15, g = lane >> 4;
    const int R0   = bid << 6;          // 64 rows per block

    // ---- h-align slice: 16 float4-pairs per thread ----
    float hp = 0.f;
    {
        int gt = (bid << 8) + tid;       // 0..262143
        const float4* hev = (const float4*)he;
        const float4* hcv = (const float4*)hc;
        #pragma unroll 4
        for (int i = 0; i < 16; ++i) {
            float4 e = hev[(size_t)i * 262144 + gt];
            float4 c = hcv[(size_t)i * 262144 + gt];
            float dx = e.x - c.x, dy = e.y - c.y, dz = e.z - c.z, dw = e.w - c.w;
            hp += dx * dx + dy * dy + dz * dz + dw * dw;
        }
    }

    // ---- A-fragments: 4 row-frags x 4 kk; q0 pos-dot, q1 zsq ----
    bf16x8_t Af[4][4];
    float sp = 0.f;
    #pragma unroll
    for (int rf = 0; rf < 4; ++rf) {
        int row = R0 + (rf << 4) + l15;
        const float4* zr = (const float4*)z + ((size_t)row << 5);
        const float4* ar;
        if (q == 0) {
            int lb = labels[row];
            ar = (const float4*)ancf + ((size_t)lb << 5);
        }
        #pragma unroll
        for (int kk = 0; kk < 4; ++kk) {
            int qq = (kk << 3) + (g << 1);
            float4 z0 = zr[qq], z1 = zr[qq + 1];
            if (q == 0) {
                float4 a0 = ar[qq], a1 = ar[qq + 1];
                sp += z0.x*a0.x + z0.y*a0.y + z0.z*a0.z + z0.w*a0.w
                    + z1.x*a1.x + z1.y*a1.y + z1.z*a1.z + z1.w*a1.w;
            } else if (q == 1) {
                sp += z0.x*z0.x + z0.y*z0.y + z0.z*z0.z + z0.w*z0.w
                    + z1.x*z1.x + z1.y*z1.y + z1.z*z1.z + z1.w*z1.w;
            }
            bf16x8_t pk;
            pk[0] = (__bf16)(z0.x * SCALE_ZB); pk[1] = (__bf16)(z0.y * SCALE_ZB);
            pk[2] = (__bf16)(z0.z * SCALE_ZB); pk[3] = (__bf16)(z0.w * SCALE_ZB);
            pk[4] = (__bf16)(z1.x * SCALE_ZB); pk[5] = (__bf16)(z1.y * SCALE_ZB);
            pk[6] = (__bf16)(z1.z * SCALE_ZB); pk[7] = (__bf16)(z1.w * SCALE_ZB);
            Af[rf][kk] = pk;
        }
    }
    #pragma unroll
    for (int off = 32; off; off >>= 1) {
        sp += __shfl_xor(sp, off);
        hp += __shfl_xor(hp, off);
    }

    // ---- main loop: 32 chunks (quarter q), 4-deep rotation, batched-2 LSE ----
    float ms[4][4], ss[4][4];
    #pragma unroll
    for (int f = 0; f < 4; ++f)
        #pragma unroll
        for (int r = 0; r < 4; ++r) { ms[f][r] = -1.0e30f; ss[f][r] = 0.f; }

    const bf16x8_t* Bp = (const bf16x8_t*)ancb + (q << 13);

#define LOADB(Bx, cc) { _Pragma("unroll") \
    for (int kk = 0; kk < 4; ++kk) Bx[kk] = Bp[((((cc) << 2) | kk) << 6) + lane]; }

#define CHUNK2(Bx, By) { \
    f32x4_t a0[4], a1[4]; \
    _Pragma("unroll") \
    for (int f = 0; f < 4; ++f) { a0[f] = (f32x4_t){0.f,0.f,0.f,0.f}; a1[f] = (f32x4_t){0.f,0.f,0.f,0.f}; } \
    _Pragma("unroll") \
    for (int kk = 0; kk < 4; ++kk) \
        _Pragma("unroll") \
        for (int f = 0; f < 4; ++f) \
            a0[f] = __builtin_amdgcn_mfma_f32_16x16x32_bf16(Af[f][kk], Bx[kk], a0[f], 0, 0, 0); \
    _Pragma("unroll") \
    for (int kk = 0; kk < 4; ++kk) \
        _Pragma("unroll") \
        for (int f = 0; f < 4; ++f) \
            a1[f] = __builtin_amdgcn_mfma_f32_16x16x32_bf16(Af[f][kk], By[kk], a1[f], 0, 0, 0); \
    _Pragma("unroll") \
    for (int f = 0; f < 4; ++f) \
        _Pragma("unroll") \
        for (int r = 0; r < 4; ++r) { \
            float v0 = a0[f][r], v1 = a1[f][r]; \
            float nm = fmaxf(fmaxf(v0, v1), ms[f][r]); \
            ss[f][r] = ss[f][r] * E2(ms[f][r] - nm) + E2(v0 - nm) + E2(v1 - nm); \
            ms[f][r] = nm; \
        } }

    bf16x8_t Ba[4], Bb[4], Bc[4], Bd[4];
    LOADB(Ba, 0) LOADB(Bb, 1) LOADB(Bc, 2) LOADB(Bd, 3)

    for (int c = 0; c < 32; c += 4) {
        CHUNK2(Ba, Bb)
        if (c < 28) { LOADB(Ba, c + 4) LOADB(Bb, c + 5) }
        CHUNK2(Bc, Bd)
        if (c < 28) { LOADB(Bc, c + 6) LOADB(Bd, c + 7) }
    }
#undef LOADB
#undef CHUNK2

    // ---- merge (m,s) across the 16 anchor-lanes; write quarter partials ----
    #pragma unroll
    for (int f = 0; f < 4; ++f)
        #pragma unroll
        for (int r = 0; r < 4; ++r) {
            float m = ms[f][r], s = ss[f][r];
            #pragma unroll
            for (int off = 1; off < 16; off <<= 1) {
                float om = __shfl_xor(m, off), os = __shfl_xor(s, off);
                float nm = fmaxf(m, om);
                s = s * E2(m - nm) + os * E2(om - nm);
                m = nm;
            }
            ms[f][r] = m; ss[f][r] = s;
        }
    if (l15 == 0) {
        #pragma unroll
        for (int f = 0; f < 4; ++f)
            #pragma unroll
            for (int r = 0; r < 4; ++r) {
                int row0 = R0 + (f << 4) + (g << 2) + r;
                part[(row0 << 2) + q] = make_float2(ms[f][r], ss[f][r]);
            }
    }

    // ---- centroid tail: waves 2,3 handle labels 2*bid, 2*bid+1 ----
    float centv = 0.f;
    if (q >= 2) {
        int lb = (bid << 1) + (q - 2);
        const int n = cnt[lb], bs = basep[lb];
        float ax = 0.f, ay = 0.f;
        const float2* z2 = (const float2*)z;
        for (int e0 = 0; e0 < n; e0 += 64) {
            int pe = (e0 + lane < n) ? perm[bs + e0 + lane] : 0;
            int c2 = n - e0; if (c2 > 64) c2 = 64;
            int j = 0;
            for (; j + 3 < c2; j += 4) {
                int r0 = __shfl(pe, j), r1 = __shfl(pe, j + 1);
                int r2 = __shfl(pe, j + 2), r3 = __shfl(pe, j + 3);
                float2 v0 = z2[((size_t)r0 << 6) + lane];
                float2 v1 = z2[((size_t)r1 << 6) + lane];
                float2 v2 = z2[((size_t)r2 << 6) + lane];
                float2 v3 = z2[((size_t)r3 << 6) + lane];
                ax += v0.x + v1.x + v2.x + v3.x;
                ay += v0.y + v1.y + v2.y + v3.y;
            }
            for (; j < c2; ++j) {
                int r0 = __shfl(pe, j);
                float2 v0 = z2[((size_t)r0 << 6) + lane];
                ax += v0.x; ay += v0.y;
            }
        }
        float ssq = ax * ax + ay * ay;
        #pragma unroll
        for (int off = 32; off; off >>= 1) ssq += __shfl_xor(ssq, off);
        centv = ssq / fmaxf((float)n, 1.f);
    }

    // ---- per-wave slot store (no atomics) ----
    if (lane == 0) {
        float4 o;
        o.x = hp;
        o.y = (q == 0) ? sp : 0.f;
        o.z = (q == 1) ? sp : 0.f;
        o.w = centv;
        wsum[(bid << 2) | q] = o;
    }
}

// ---- merge the four M-quarter partials per row -> per-block lse partial ----
__global__ void mergeL(const float4* __restrict__ part4, float* __restrict__ lsePart) {
    __shared__ float wpart[4];
    int t = blockIdx.x * 256 + threadIdx.x;   // 0..65535 rows
    float4 A = part4[t << 1], Bq = part4[(t << 1) + 1];
    float nm = fmaxf(fmaxf(A.x, A.z), fmaxf(Bq.x, Bq.z));
    float s = A.y * E2(A.x - nm) + A.w * E2(A.z - nm)
            + Bq.y * E2(Bq.x - nm) + Bq.w * E2(Bq.z - nm);
    float lse = nm + LG2(s);
    #pragma unroll
    for (int off = 32; off; off >>= 1) lse += __shfl_xor(lse, off);
    if ((threadIdx.x & 63) == 0) wpart[threadIdx.x >> 6] = lse;
    __syncthreads();
    if (threadIdx.x == 0)
        lsePart[blockIdx.x] = wpart[0] + wpart[1] + wpart[2] + wpart[3];
}

// ---- final reduction: 4096 wave slots + 256 lse partials ----
__global__ void finalR(const float4* __restrict__ wsum,
                       const float* __restrict__ lsePart,
                       float* __restrict__ out) {
    __shared__ float red[5][4];
    int t = threadIdx.x, lane = t & 63, w = t >> 6;
    float hp = 0.f, pos = 0.f, zsq = 0.f, cent = 0.f, lse = 0.f;
    #pragma unroll
    for (int i = 0; i < 16; ++i) {
        float4 v = wsum[i * 256 + t];
        hp += v.x; pos += v.y; zsq += v.z; cent += v.w;
    }
    lse = lsePart[t];
    #pragma unroll
    for (int off = 32; off; off >>= 1) {
        hp  += __shfl_xor(hp, off);
        pos += __shfl_xor(pos, off);
        zsq += __shfl_xor(zsq, off);
        cent += __shfl_xor(cent, off);
        lse += __shfl_xor(lse, off);
    }
    if (lane == 0) {
        red[0][w] = hp; red[1][w] = pos; red[2][w] = zsq; red[3][w] = cent; red[4][w] = lse;
    }
    __syncthreads();
    if (t == 0) {
        float H = red[0][0] + red[0][1] + red[0][2] + red[0][3];
        float P = red[1][0] + red[1][1] + red[1][2] + red[1][3];
        float Z = red[2][0] + red[2][1] + red[2][2] + red[2][3];
        float C = red[3][0] + red[3][1] + red[3][2] + red[3][3];
        float L = red[4][0] + red[4][1] + red[4][2] + red[4][3];
        float lc    = (LN2 * L - 5.0f * P) * (1.0f / 65536.0f);
        float cent2 = (Z - C) * (1.0f / 8388608.0f);
        float hal   = H * (1.0f / 16777216.0f);
        out[0] = lc + 0.05f * cent2 + 0.1f * hal;
    }
}

extern "C" void kernel_launch(void* const* d_in, const int* in_sizes, int n_in,
                              void* d_out, int out_size, void* d_ws, size_t ws_size,
                              hipStream_t stream) {
    const float* z      = (const float*)d_in[0];
    const float* he     = (const float*)d_in[1];
    const float* hc     = (const float*)d_in[2];
    const float* anc    = (const float*)d_in[3];
    const int*   labels = (const int*)d_in[4];

    char* ws = (char*)d_ws;
    int*    cnt     = (int*)(ws + WS_CNT);
    int*    basep   = (int*)(ws + WS_BASE);
    int*    cursor  = (int*)(ws + WS_CUR);
    int*    perm    = (int*)(ws + WS_PERM);
    __bf16* ancb    = (__bf16*)(ws + WS_ANC);
    float2* part    = (float2*)(ws + WS_PART);
    float4* wsum    = (float4*)(ws + WS_WSUM);
    float*  lsePart = (float*)(ws + WS_LSE);

    hipMemsetAsync(d_ws, 0, WS_ZERO, stream);
    prepHist<<<256, 256, 0, stream>>>(anc, ancb, labels, cnt);
    scanK<<<1, 256, 0, stream>>>(cnt, basep, cursor);
    scatK<<<256, 256, 0, stream>>>(labels, cursor, perm);
    uniK2<<<1024, 256, 0, stream>>>(z, he, hc, anc, labels, ancb, cnt, basep, perm, wsum, part);
    mergeL<<<256, 256, 0, stream>>>((const float4*)part, lsePart);
    finalR<<<1, 256, 0, stream>>>(wsum, lsePart, (float*)d_out);
}

// Round 14
// 131.521 us; speedup vs baseline: 1.1306x; 1.1023x over previous
//
#include <hip/hip_runtime.h>
#include <hip/hip_bf16.h>

typedef __bf16 bf16x8_t __attribute__((ext_vector_type(8)));
typedef float f32x4_t __attribute__((ext_vector_type(4)));

#define SCALE_ZB 7.2134752044448169f   // 5 * log2(e): logits in log2 domain
#define LN2 0.69314718055994531f
#define E2(x) __builtin_amdgcn_exp2f(x)
#define LG2(x) __builtin_amdgcn_logf(x)

// ws byte offsets
#define WS_CNT    256u       // int[2048]
#define WS_BASE   8448u      // int[2048]
#define WS_CUR    16640u     // int[2048]
#define WS_PERM   24832u     // int[65536]
#define WS_ANC    294912u    // bf16[262144] (512 KB), B-fragment order
#define WS_PART   819200u    // float2[65536*4] = 2 MB
#define WS_WSUM   2916352u   // float4[8192] (hp,pos,zsq,cent per H-wave)
#define WS_LSE    3047424u   // float[256]
#define WS_ZERO   8448u      // zero cnt region only

// ---- anchors f32 -> bf16 packed in MFMA B-fragment order + label histogram ----
// layout: [chunk c 0..127][kk 0..3][lane 0..63][e 0..7]
__global__ void prepHist(const float* __restrict__ anc, __bf16* __restrict__ out,
                         const int* __restrict__ labels, int* __restrict__ cnt) {
    int i = blockIdx.x * 256 + threadIdx.x;   // 0..65535
    atomicAdd(&cnt[labels[i]], 1);
    if (i < 32768) {
        int m = i >> 4, k0 = (i & 15) << 3;
        int kk = k0 >> 5, g = (k0 >> 3) & 3, l15 = m & 15, c = m >> 4;
        int lane = (g << 4) | l15;
        int base = (((c << 2) + kk) << 9) + (lane << 3);
        const float4* a4 = (const float4*)anc + (size_t)m * 32 + (k0 >> 2);
        float4 f0 = a4[0], f1 = a4[1];
        bf16x8_t pk;
        pk[0] = (__bf16)f0.x; pk[1] = (__bf16)f0.y; pk[2] = (__bf16)f0.z; pk[3] = (__bf16)f0.w;
        pk[4] = (__bf16)f1.x; pk[5] = (__bf16)f1.y; pk[6] = (__bf16)f1.z; pk[7] = (__bf16)f1.w;
        *(bf16x8_t*)&out[base] = pk;
    }
}

__global__ void scanK(const int* __restrict__ cnt, int* __restrict__ base,
                      int* __restrict__ cursor) {
    __shared__ int wsum[4];
    int t = threadIdx.x, lane = t & 63, w = t >> 6;
    int c[8], tot = 0;
    #pragma unroll
    for (int q = 0; q < 8; ++q) { c[q] = cnt[t * 8 + q]; tot += c[q]; }
    int sc = tot;
    #pragma unroll
    for (int off = 1; off < 64; off <<= 1) {
        int o = __shfl_up(sc, off);
        if (lane >= off) sc += o;
    }
    if (lane == 63) wsum[w] = sc;
    __syncthreads();
    int woff = 0;
    for (int ww = 0; ww < w; ++ww) woff += wsum[ww];
    int ex = woff + sc - tot;
    #pragma unroll
    for (int q = 0; q < 8; ++q) {
        base[t * 8 + q] = ex;
        cursor[t * 8 + q] = ex;
        ex += c[q];
    }
}

__global__ void scatK(const int* __restrict__ labels, int* __restrict__ cursor,
                      int* __restrict__ perm) {
    int i = blockIdx.x * 256 + threadIdx.x;
    int l = labels[i];
    int p = atomicAdd(&cursor[l], 1);
    perm[p] = i;
}

// Heterogeneous 3072 blocks x 256 thr, role = bid % 3:
//  role 0 (1024 blocks): GEMM — 4 waves, SAME quarter q, 4 different 64-row
//    groups (L1-shared B-stream), staggered chunk start (L2 decorrelation).
//  role 1,2 (2048 blocks): H — h-slice + pos/zsq (32 rows) + cent (wave 0).
// Zero global atomics; per-wave slot stores.
__launch_bounds__(256)
__global__ void megaF(const float* __restrict__ z,
                      const float* __restrict__ he,
                      const float* __restrict__ hc,
                      const float* __restrict__ ancf,
                      const int* __restrict__ labels,
                      const __bf16* __restrict__ ancb,
                      const int* __restrict__ cnt,
                      const int* __restrict__ basep,
                      const int* __restrict__ perm,
                      float4* __restrict__ wsum,
                      float2* __restrict__ part) {
    const int tid  = threadIdx.x;
    const int lane = tid & 63;
    const int w    = tid >> 6;
    const int bid  = blockIdx.x;
    const int role = bid % 3;
    const int idx3 = bid / 3;

    if (role == 0) {
        // ================= GEMM role =================
        const int l15 = lane & 15, g = lane >> 4;
        const int q   = idx3 & 3;           // quarter (shared by all 4 waves)
        const int b4  = idx3 >> 2;          // 0..255
        const int rg  = (b4 << 2) + w;      // wave's row-group 0..1023
        const int R0  = rg << 6;            // 64 rows
        const int c0  = (b4 * 7 + q * 11) & 31;   // staggered chunk start

        // ---- A-fragments: 4 row-frags x 4 kk ----
        bf16x8_t Af[4][4];
        #pragma unroll
        for (int rf = 0; rf < 4; ++rf) {
            int row = R0 + (rf << 4) + l15;
            const float4* zr = (const float4*)z + ((size_t)row << 5);
            #pragma unroll
            for (int kk = 0; kk < 4; ++kk) {
                int qq = (kk << 3) + (g << 1);
                float4 z0 = zr[qq], z1 = zr[qq + 1];
                bf16x8_t pk;
                pk[0] = (__bf16)(z0.x * SCALE_ZB); pk[1] = (__bf16)(z0.y * SCALE_ZB);
                pk[2] = (__bf16)(z0.z * SCALE_ZB); pk[3] = (__bf16)(z0.w * SCALE_ZB);
                pk[4] = (__bf16)(z1.x * SCALE_ZB); pk[5] = (__bf16)(z1.y * SCALE_ZB);
                pk[6] = (__bf16)(z1.z * SCALE_ZB); pk[7] = (__bf16)(z1.w * SCALE_ZB);
                Af[rf][kk] = pk;
            }
        }

        float ms[4][4], ss[4][4];
        #pragma unroll
        for (int f = 0; f < 4; ++f)
            #pragma unroll
            for (int r = 0; r < 4; ++r) { ms[f][r] = -1.0e30f; ss[f][r] = 0.f; }

        const bf16x8_t* Bp = (const bf16x8_t*)ancb + (q << 13);

#define LOADB(Bx, ii) { int CC = (c0 + (ii)) & 31; _Pragma("unroll") \
        for (int kk = 0; kk < 4; ++kk) Bx[kk] = Bp[(((CC << 2) | kk) << 6) + lane]; }

#define CHUNK2(Bx, By) { \
        f32x4_t a0[4], a1[4]; \
        _Pragma("unroll") \
        for (int f = 0; f < 4; ++f) { a0[f] = (f32x4_t){0.f,0.f,0.f,0.f}; a1[f] = (f32x4_t){0.f,0.f,0.f,0.f}; } \
        _Pragma("unroll") \
        for (int kk = 0; kk < 4; ++kk) \
            _Pragma("unroll") \
            for (int f = 0; f < 4; ++f) \
                a0[f] = __builtin_amdgcn_mfma_f32_16x16x32_bf16(Af[f][kk], Bx[kk], a0[f], 0, 0, 0); \
        _Pragma("unroll") \
        for (int kk = 0; kk < 4; ++kk) \
            _Pragma("unroll") \
            for (int f = 0; f < 4; ++f) \
                a1[f] = __builtin_amdgcn_mfma_f32_16x16x32_bf16(Af[f][kk], By[kk], a1[f], 0, 0, 0); \
        _Pragma("unroll") \
        for (int f = 0; f < 4; ++f) \
            _Pragma("unroll") \
            for (int r = 0; r < 4; ++r) { \
                float v0 = a0[f][r], v1 = a1[f][r]; \
                float nm = fmaxf(fmaxf(v0, v1), ms[f][r]); \
                ss[f][r] = ss[f][r] * E2(ms[f][r] - nm) + E2(v0 - nm) + E2(v1 - nm); \
                ms[f][r] = nm; \
            } }

        bf16x8_t Ba[4], Bb[4], Bc[4], Bd[4];
        LOADB(Ba, 0) LOADB(Bb, 1) LOADB(Bc, 2) LOADB(Bd, 3)

        for (int c = 0; c < 32; c += 4) {
            CHUNK2(Ba, Bb)
            if (c < 28) { LOADB(Ba, c + 4) LOADB(Bb, c + 5) }
            CHUNK2(Bc, Bd)
            if (c < 28) { LOADB(Bc, c + 6) LOADB(Bd, c + 7) }
        }
#undef LOADB
#undef CHUNK2

        // ---- merge (m,s) across the 16 anchor-lanes; write quarter partials ----
        #pragma unroll
        for (int f = 0; f < 4; ++f)
            #pragma unroll
            for (int r = 0; r < 4; ++r) {
                float m = ms[f][r], s = ss[f][r];
                #pragma unroll
                for (int off = 1; off < 16; off <<= 1) {
                    float om = __shfl_xor(m, off), os = __shfl_xor(s, off);
                    float nm = fmaxf(m, om);
                    s = s * E2(m - nm) + os * E2(om - nm);
                    m = nm;
                }
                ms[f][r] = m; ss[f][r] = s;
            }
        if (l15 == 0) {
            #pragma unroll
            for (int f = 0; f < 4; ++f)
                #pragma unroll
                for (int r = 0; r < 4; ++r) {
                    int row0 = R0 + (f << 4) + (g << 2) + r;
                    part[(row0 << 2) + q] = make_float2(ms[f][r], ss[f][r]);
                }
        }

    } else {
        // ================= H role =================
        const int h = (idx3 << 1) + (role - 1);   // 0..2047

        // ---- h-align slice: 8 float4-pairs per thread ----
        float hp = 0.f;
        {
            int gt = (h << 8) + tid;              // 0..524287
            const float4* hev = (const float4*)he;
            const float4* hcv = (const float4*)hc;
            #pragma unroll 4
            for (int i = 0; i < 8; ++i) {
                float4 e = hev[(size_t)i * 524288 + gt];
                float4 c = hcv[(size_t)i * 524288 + gt];
                float dx = e.x - c.x, dy = e.y - c.y, dz = e.z - c.z, dw = e.w - c.w;
                hp += dx * dx + dy * dy + dz * dz + dw * dw;
            }
        }

        // ---- pos-dot + zsq over rows h*32..+32 ----
        float pos = 0.f, zsq = 0.f;
        const int R = h << 5;
        #pragma unroll
        for (int i = 0; i < 4; ++i) {
            int idx = (i << 8) + tid;
            int r = idx >> 5, c4 = idx & 31;
            int row = R + r;
            int lb = labels[row];
            float4 zv = ((const float4*)z)[((size_t)row << 5) + c4];
            float4 av = ((const float4*)ancf)[((size_t)lb << 5) + c4];
            pos += zv.x*av.x + zv.y*av.y + zv.z*av.z + zv.w*av.w;
            zsq += zv.x*zv.x + zv.y*zv.y + zv.z*zv.z + zv.w*zv.w;
        }

        #pragma unroll
        for (int off = 32; off; off >>= 1) {
            hp  += __shfl_xor(hp, off);
            pos += __shfl_xor(pos, off);
            zsq += __shfl_xor(zsq, off);
        }

        // ---- centroid: wave 0 handles label h ----
        float centv = 0.f;
        if (w == 0) {
            const int n = cnt[h], bs = basep[h];
            float ax = 0.f, ay = 0.f;
            const float2* z2 = (const float2*)z;
            for (int e0 = 0; e0 < n; e0 += 64) {
                int pe = (e0 + lane < n) ? perm[bs + e0 + lane] : 0;
                int c2 = n - e0; if (c2 > 64) c2 = 64;
                int j = 0;
                for (; j + 3 < c2; j += 4) {
                    int r0 = __shfl(pe, j), r1 = __shfl(pe, j + 1);
                    int r2 = __shfl(pe, j + 2), r3 = __shfl(pe, j + 3);
                    float2 v0 = z2[((size_t)r0 << 6) + lane];
                    float2 v1 = z2[((size_t)r1 << 6) + lane];
                    float2 v2 = z2[((size_t)r2 << 6) + lane];
                    float2 v3 = z2[((size_t)r3 << 6) + lane];
                    ax += v0.x + v1.x + v2.x + v3.x;
                    ay += v0.y + v1.y + v2.y + v3.y;
                }
                for (; j < c2; ++j) {
                    int r0 = __shfl(pe, j);
                    float2 v0 = z2[((size_t)r0 << 6) + lane];
                    ax += v0.x; ay += v0.y;
                }
            }
            float ssq = ax * ax + ay * ay;
            #pragma unroll
            for (int off = 32; off; off >>= 1) ssq += __shfl_xor(ssq, off);
            centv = ssq / fmaxf((float)n, 1.f);
        }

        if (lane == 0)
            wsum[(h << 2) | w] = make_float4(hp, pos, zsq, centv);
    }
}

// ---- merge the four M-quarter partials per row -> per-block lse partial ----
__global__ void mergeL(const float4* __restrict__ part4, float* __restrict__ lsePart) {
    __shared__ float wpart[4];
    int t = blockIdx.x * 256 + threadIdx.x;   // 0..65535 rows
    float4 A = part4[t << 1], Bq = part4[(t << 1) + 1];
    float nm = fmaxf(fmaxf(A.x, A.z), fmaxf(Bq.x, Bq.z));
    float s = A.y * E2(A.x - nm) + A.w * E2(A.z - nm)
            + Bq.y * E2(Bq.x - nm) + Bq.w * E2(Bq.z - nm);
    float lse = nm + LG2(s);
    #pragma unroll
    for (int off = 32; off; off >>= 1) lse += __shfl_xor(lse, off);
    if ((threadIdx.x & 63) == 0) wpart[threadIdx.x >> 6] = lse;
    __syncthreads();
    if (threadIdx.x == 0)
        lsePart[blockIdx.x] = wpart[0] + wpart[1] + wpart[2] + wpart[3];
}

// ---- final reduction: 8192 wave slots + 256 lse partials ----
__global__ void finalR(const float4* __restrict__ wsum,
                       const float* __restrict__ lsePart,
                       float* __restrict__ out) {
    __shared__ float red[5][4];
    int t = threadIdx.x, lane = t & 63, w = t >> 6;
    float hp = 0.f, pos = 0.f, zsq = 0.f, cent = 0.f, lse = 0.f;
    #pragma unroll
    for (int i = 0; i < 32; ++i) {
        float4 v = wsum[i * 256 + t];
        hp += v.x; pos += v.y; zsq += v.z; cent += v.w;
    }
    lse = lsePart[t];
    #pragma unroll
    for (int off = 32; off; off >>= 1) {
        hp  += __shfl_xor(hp, off);
        pos += __shfl_xor(pos, off);
        zsq += __shfl_xor(zsq, off);
        cent += __shfl_xor(cent, off);
        lse += __shfl_xor(lse, off);
    }
    if (lane == 0) {
        red[0][w] = hp; red[1][w] = pos; red[2][w] = zsq; red[3][w] = cent; red[4][w] = lse;
    }
    __syncthreads();
    if (t == 0) {
        float H = red[0][0] + red[0][1] + red[0][2] + red[0][3];
        float P = red[1][0] + red[1][1] + red[1][2] + red[1][3];
        float Z = red[2][0] + red[2][1] + red[2][2] + red[2][3];
        float C = red[3][0] + red[3][1] + red[3][2] + red[3][3];
        float L = red[4][0] + red[4][1] + red[4][2] + red[4][3];
        float lc    = (LN2 * L - 5.0f * P) * (1.0f / 65536.0f);
        float cent2 = (Z - C) * (1.0f / 8388608.0f);
        float hal   = H * (1.0f / 16777216.0f);
        out[0] = lc + 0.05f * cent2 + 0.1f * hal;
    }
}

extern "C" void kernel_launch(void* const* d_in, const int* in_sizes, int n_in,
                              void* d_out, int out_size, void* d_ws, size_t ws_size,
                              hipStream_t stream) {
    const float* z      = (const float*)d_in[0];
    const float* he     = (const float*)d_in[1];
    const float* hc     = (const float*)d_in[2];
    const float* anc    = (const float*)d_in[3];
    const int*   labels = (const int*)d_in[4];

    char* ws = (char*)d_ws;
    int*    cnt     = (int*)(ws + WS_CNT);
    int*    basep   = (int*)(ws + WS_BASE);
    int*    cursor  = (int*)(ws + WS_CUR);
    int*    perm    = (int*)(ws + WS_PERM);
    __bf16* ancb    = (__bf16*)(ws + WS_ANC);
    float2* part    = (float2*)(ws + WS_PART);
    float4* wsum    = (float4*)(ws + WS_WSUM);
    float*  lsePart = (float*)(ws + WS_LSE);

    hipMemsetAsync(d_ws, 0, WS_ZERO, stream);
    prepHist<<<256, 256, 0, stream>>>(anc, ancb, labels, cnt);
    scanK<<<1, 256, 0, stream>>>(cnt, basep, cursor);
    scatK<<<256, 256, 0, stream>>>(labels, cursor, perm);
    megaF<<<3072, 256, 0, stream>>>(z, he, hc, anc, labels, ancb, cnt, basep, perm, wsum, part);
    mergeL<<<256, 256, 0, stream>>>((const float4*)part, lsePart);
    finalR<<<1, 256, 0, stream>>>(wsum, lsePart, (float*)d_out);
}